// Round 1
// baseline (105.236 us; speedup 1.0000x reference)
//
#include <hip/hip_runtime.h>
#include <hip/hip_cooperative_groups.h>

// L1 "order" Chamfer loss, per-coordinate min, mean-reduced to a scalar.
// pred/target: (8192, 128) fp32 = 8192 rows x (64 points x 2 coords).
//
// Fused single cooperative kernel (was: partial kernel + reduce kernel).
// The compute is ~2 us of work (8 MiB read, ~256 VALU ops/wave-row); the
// previous 2-node graph paid a second dispatch + inter-node gap just to sum
// 512 partials. Now: 256 blocks x 1024 threads = exactly 1 block/CU
// (compiler caps VGPR at 128 for a 1024-thread block, so cooperative
// co-residency is guaranteed), each wave does 2 rows, partials -> d_ws,
// grid.sync(), block 0 reduces 256 partials and plain-stores out[0].
//
// Per-row math: one wave per row. Lane i owns pred point i and target
// point i (coalesced float2 loads). The j-broadcast stream is read as
// wave-uniform float4 chunks (2 points each -> scalar s_load path); subs
// vectorize to v_pk_add_f32 and the two mins per accumulator fold to
// v_min3_f32 with |.| modifiers: 8 VALU per 2 points.

#define GRID 256
#define BLOCK 1024
#define WPB (BLOCK / 64)   // 16 waves per block
#define RPW 2              // rows per wave: 256 * 16 * 2 = 8192 rows
#define ROW_FLOATS 128
#define NCHUNK 32          // 32 float4 chunks = 64 points

typedef float vf4 __attribute__((ext_vector_type(4)));

namespace cg = cooperative_groups;

__global__ __launch_bounds__(BLOCK)
void l1_order_fused_kernel(const float* __restrict__ pred,
                           const float* __restrict__ target,
                           float* __restrict__ partials,
                           float* __restrict__ out) {
    __shared__ float wsum[WPB];

    const int t = threadIdx.x;
    const int lane = t & 63;
    const int w = t >> 6;

    float acc = 0.0f;

    #pragma unroll 1   // keep VGPR pressure low; inner loop is fully unrolled
    for (int r = 0; r < RPW; ++r) {
        const int row = __builtin_amdgcn_readfirstlane(
            (blockIdx.x * WPB + w) * RPW + r);

        const float* __restrict__ rp = pred   + (size_t)row * ROW_FLOATS;
        const float* __restrict__ rt = target + (size_t)row * ROW_FLOATS;

        // Divergent per-lane points: one coalesced 8B load each.
        const float2 pi = ((const float2*)rp)[lane];
        const float2 ti = ((const float2*)rt)[lane];
        const vf4 piv = {pi.x, pi.y, pi.x, pi.y};
        const vf4 tiv = {ti.x, ti.y, ti.x, ti.y};

        float m1x = 1e30f, m1y = 1e30f;  // dist_1: min over target points j
        float m2x = 1e30f, m2y = 1e30f;  // dist_2: min over pred points j

        const vf4* __restrict__ rt4 = (const vf4*)rt;
        const vf4* __restrict__ rp4 = (const vf4*)rp;

        #pragma unroll
        for (int c = 0; c < NCHUNK; ++c) {
            const vf4 dt = piv - rt4[c];   // 2x v_pk_add_f32 (neg)
            const vf4 dp = tiv - rp4[c];
            // v_min3_f32 with |.| input modifiers: 1 instr per accumulator.
            m1x = fminf(fminf(fabsf(dt.x), fabsf(dt.z)), m1x);
            m1y = fminf(fminf(fabsf(dt.y), fabsf(dt.w)), m1y);
            m2x = fminf(fminf(fabsf(dp.x), fabsf(dp.z)), m2x);
            m2y = fminf(fminf(fabsf(dp.y), fabsf(dp.w)), m2y);
        }

        acc += (m1x + m1y) + (m2x + m2y);
    }

    // Wave reduction (64 lanes), then block reduction via LDS.
    #pragma unroll
    for (int off = 32; off > 0; off >>= 1)
        acc += __shfl_down(acc, off);

    if (lane == 0) wsum[w] = acc;
    __syncthreads();

    if (t == 0) {
        float s = 0.0f;
        #pragma unroll
        for (int i = 0; i < WPB; ++i) s += wsum[i];
        partials[blockIdx.x] = s;   // plain store into d_ws
        __threadfence();            // device-scope visibility before grid sync
    }

    cg::this_grid().sync();

    // Block 0 reduces the 256 per-block partials and writes the scalar.
    if (blockIdx.x == 0) {
        float p = (t < GRID) ? partials[t] : 0.0f;

        #pragma unroll
        for (int off = 32; off > 0; off >>= 1)
            p += __shfl_down(p, off);

        if (lane == 0) wsum[w] = p;   // safe: grid sync is also a block barrier
        __syncthreads();

        if (t == 0) {
            float s = 0.0f;
            #pragma unroll
            for (int i = 0; i < WPB; ++i) s += wsum[i];
            // scale = 0.5 / (8192 * 128 * 64) = 2^-27 (exact)
            out[0] = s * 7.450580596923828e-09f;
        }
    }
}

extern "C" void kernel_launch(void* const* d_in, const int* in_sizes, int n_in,
                              void* d_out, int out_size, void* d_ws, size_t ws_size,
                              hipStream_t stream) {
    const float* pred   = (const float*)d_in[0];
    const float* target = (const float*)d_in[1];
    float* out = (float*)d_out;
    float* partials = (float*)d_ws;

    // Fixed problem shape: 8192 rows x 128 floats (asserted by GRID*WPB*RPW).
    void* args[] = {(void*)&pred, (void*)&target, (void*)&partials, (void*)&out};
    hipLaunchCooperativeKernel((void*)l1_order_fused_kernel,
                               dim3(GRID), dim3(BLOCK), args, 0, stream);
}

// Round 2
// 64.216 us; speedup vs baseline: 1.6388x; 1.6388x over previous
//
#include <hip/hip_runtime.h>

// L1 "order" Chamfer loss, per-coordinate min, mean-reduced to a scalar.
// pred/target: (8192, 128) fp32 = 8192 rows x (64 points x 2 coords).
//
// SINGLE plain kernel node (round-1 lesson: hipLaunchCooperativeKernel costs
// ~40us on this harness -- grid.sync worked but the dispatch path regressed
// 63.6 -> 105.2us; reverted). The 2nd reduce node is eliminated instead via an
// init-free grid handshake:
//   - each block's leader publishes its partial as a self-validating 8-byte
//     entry {hi = ~bits(v) ^ SALT, lo = bits(v)} with a device-scope atomic
//     store into d_ws (single-copy atomic => pair always consistent),
//   - block 0 spins with device-scope atomic loads (one entry per thread)
//     until all 256 entries validate, then reduces and plain-stores out[0].
// No memset node: no constant (c == ~c^SALT impossible for the fill pattern
// to satisfy: would need c == ~c ^ 0x5A5A5A5A, i.e. specific crafted bytes)
// or complement poison pattern validates. Deadlock-free: only block 0 waits,
// and 256 blocks = 1 block/CU are all resident. Cross-XCD visibility via
// __HIP_MEMORY_SCOPE_AGENT (per-XCD L2s are not coherent for plain loads).
// Re-poison-safe: ws is re-filled before each iteration; even a stale entry
// would hold the identical deterministic value.
//
// Per-row math (unchanged, proven): one wave per row. Lane i owns pred point
// i and target point i (coalesced float2 loads). The j-broadcast stream is
// read as wave-uniform float4 chunks (scalar s_load path); subs vectorize to
// v_pk_add_f32 and the two mins per accumulator fold to v_min3_f32 with |.|
// modifiers: 8 VALU per 2 points.

#define GRID 256
#define BLOCK 1024
#define WPB (BLOCK / 64)   // 16 waves per block
#define RPW 2              // rows per wave: 256 * 16 * 2 = 8192 rows
#define ROW_FLOATS 128
#define NCHUNK 32          // 32 float4 chunks = 64 points
#define SALT 0x5A5A5A5Au

typedef float vf4 __attribute__((ext_vector_type(4)));

__device__ __forceinline__ unsigned long long pack_entry(float v) {
    const unsigned lo = __float_as_uint(v);
    const unsigned hi = ~lo ^ SALT;
    return ((unsigned long long)hi << 32) | (unsigned long long)lo;
}

__global__ __launch_bounds__(BLOCK)
void l1_order_onepass_kernel(const float* __restrict__ pred,
                             const float* __restrict__ target,
                             unsigned long long* __restrict__ partials,
                             float* __restrict__ out) {
    __shared__ float wsum[WPB];

    const int t = threadIdx.x;
    const int lane = t & 63;
    const int w = t >> 6;

    float acc = 0.0f;

    #pragma unroll 1   // keep VGPR pressure low; inner loop is fully unrolled
    for (int r = 0; r < RPW; ++r) {
        const int row = __builtin_amdgcn_readfirstlane(
            (blockIdx.x * WPB + w) * RPW + r);

        const float* __restrict__ rp = pred   + (size_t)row * ROW_FLOATS;
        const float* __restrict__ rt = target + (size_t)row * ROW_FLOATS;

        // Divergent per-lane points: one coalesced 8B load each.
        const float2 pi = ((const float2*)rp)[lane];
        const float2 ti = ((const float2*)rt)[lane];
        const vf4 piv = {pi.x, pi.y, pi.x, pi.y};
        const vf4 tiv = {ti.x, ti.y, ti.x, ti.y};

        float m1x = 1e30f, m1y = 1e30f;  // dist_1: min over target points j
        float m2x = 1e30f, m2y = 1e30f;  // dist_2: min over pred points j

        const vf4* __restrict__ rt4 = (const vf4*)rt;
        const vf4* __restrict__ rp4 = (const vf4*)rp;

        #pragma unroll
        for (int c = 0; c < NCHUNK; ++c) {
            const vf4 dt = piv - rt4[c];   // 2x v_pk_add_f32 (neg)
            const vf4 dp = tiv - rp4[c];
            // v_min3_f32 with |.| input modifiers: 1 instr per accumulator.
            m1x = fminf(fminf(fabsf(dt.x), fabsf(dt.z)), m1x);
            m1y = fminf(fminf(fabsf(dt.y), fabsf(dt.w)), m1y);
            m2x = fminf(fminf(fabsf(dp.x), fabsf(dp.z)), m2x);
            m2y = fminf(fminf(fabsf(dp.y), fabsf(dp.w)), m2y);
        }

        acc += (m1x + m1y) + (m2x + m2y);
    }

    // Wave reduction (64 lanes), then block reduction via LDS.
    #pragma unroll
    for (int off = 32; off > 0; off >>= 1)
        acc += __shfl_down(acc, off);

    if (lane == 0) wsum[w] = acc;
    __syncthreads();

    if (t == 0) {
        float s = 0.0f;
        #pragma unroll
        for (int i = 0; i < WPB; ++i) s += wsum[i];
        // Publish self-validating entry, device scope (cross-XCD visible).
        __hip_atomic_store(&partials[blockIdx.x], pack_entry(s),
                           __ATOMIC_RELAXED, __HIP_MEMORY_SCOPE_AGENT);
    }

    if (blockIdx.x != 0) return;   // whole non-0 blocks exit; barrier below
                                   // only involves block 0's (all-alive) waves

    __syncthreads();   // wsum reuse: t==0 above must finish reading it

    // One entry per thread (t < 256): spin until the pair validates.
    float pv = 0.0f;
    if (t < GRID) {
        unsigned long long e;
        unsigned lo, hi;
        do {
            e = __hip_atomic_load(&partials[t],
                                  __ATOMIC_RELAXED, __HIP_MEMORY_SCOPE_AGENT);
            lo = (unsigned)e;
            hi = (unsigned)(e >> 32);
        } while (hi != (~lo ^ SALT));
        pv = __uint_as_float(lo);
    }

    #pragma unroll
    for (int off = 32; off > 0; off >>= 1)
        pv += __shfl_down(pv, off);

    if (lane == 0) wsum[w] = pv;   // waves 4..15 contribute 0
    __syncthreads();

    if (t == 0) {
        float s = 0.0f;
        #pragma unroll
        for (int i = 0; i < WPB; ++i) s += wsum[i];
        // scale = 0.5 / (8192 * 128 * 64) = 2^-27 (exact)
        out[0] = s * 7.450580596923828e-09f;
    }
}

extern "C" void kernel_launch(void* const* d_in, const int* in_sizes, int n_in,
                              void* d_out, int out_size, void* d_ws, size_t ws_size,
                              hipStream_t stream) {
    const float* pred   = (const float*)d_in[0];
    const float* target = (const float*)d_in[1];
    float* out = (float*)d_out;
    unsigned long long* partials = (unsigned long long*)d_ws;

    l1_order_onepass_kernel<<<GRID, BLOCK, 0, stream>>>(pred, target,
                                                        partials, out);
}